// Round 4
// baseline (8282.226 us; speedup 1.0000x reference)
//
#include <hip/hip_runtime.h>
#include <hip/hip_bf16.h>
#include <stdint.h>

#define NSTEP 64
#define BATCH 32
#define EMBED_D 1536
#define ACT_D 16
#define DETER 2048
#define STOCH 512
#define HIDDEN 1024
#define FEAT 2560
#define NBLK 256

typedef __attribute__((ext_vector_type(8))) short bf16x8;
typedef __attribute__((ext_vector_type(4))) float f32x4;

#define MFMA16 __builtin_amdgcn_mfma_f32_16x16x32_bf16

__device__ __forceinline__ float eluf(float x) { return x > 0.f ? x : expf(x) - 1.f; }
__device__ __forceinline__ float sigf(float x) { return 1.f / (1.f + expf(-x)); }
__device__ __forceinline__ unsigned short f2bf(float f) {
    __hip_bfloat16 h = __float2bfloat16(f);
    return __builtin_bit_cast(unsigned short, h);
}
__device__ __forceinline__ float bf2f(unsigned short u) {
    unsigned v = ((unsigned)u) << 16;
    return __builtin_bit_cast(float, v);
}

// ---------------- monotonic-counter grid barrier (correct: blocks cannot pass
// barrier k until all 256 arrivals for k are in; counter never resets in-kernel)
__device__ __forceinline__ void gbar(unsigned* ctr, unsigned target) {
    __syncthreads();
    if (threadIdx.x == 0) {
        __threadfence();  // release
        __hip_atomic_fetch_add(ctr, 1u, __ATOMIC_RELAXED, __HIP_MEMORY_SCOPE_AGENT);
        while (__hip_atomic_load(ctr, __ATOMIC_RELAXED, __HIP_MEMORY_SCOPE_AGENT) < target)
            __builtin_amdgcn_s_sleep(2);
        __threadfence();  // acquire
    }
    __syncthreads();
}

// ---------------- f32 -> bf16 bulk convert
__global__ __launch_bounds__(256) void k_cvt(const float* __restrict__ src,
                                             unsigned short* __restrict__ dst, int n)
{
    int i = (blockIdx.x * 256 + threadIdx.x) * 4;
    if (i < n) {
        float4 v = *reinterpret_cast<const float4*>(src + i);
        ushort4 o;
        o.x = f2bf(v.x); o.y = f2bf(v.y); o.z = f2bf(v.z); o.w = f2bf(v.w);
        *reinterpret_cast<ushort4*>(dst + i) = o;
    }
}

// ---------------- setup: premasked h0 (f32+bf16), premasked z0 (bf16), ctr=0
__global__ __launch_bounds__(256) void k_setup(
    const float* __restrict__ h0, const float* __restrict__ z0,
    const uint8_t* __restrict__ reset0,
    float* __restrict__ h0m, unsigned short* __restrict__ h16m0,
    unsigned short* __restrict__ z16m, unsigned* __restrict__ ctr)
{
    int idx = (blockIdx.x * 256 + threadIdx.x) * 4;
    if (idx < BATCH * DETER) {
        int b = idx >> 11;
        float m = reset0[b] ? 0.f : 1.f;
        float4 v = *reinterpret_cast<const float4*>(h0 + idx);
        v.x *= m; v.y *= m; v.z *= m; v.w *= m;
        *reinterpret_cast<float4*>(h0m + idx) = v;
        ushort4 o;
        o.x = f2bf(v.x); o.y = f2bf(v.y); o.z = f2bf(v.z); o.w = f2bf(v.w);
        *reinterpret_cast<ushort4*>(h16m0 + idx) = o;
    } else if (idx < BATCH * DETER + BATCH * STOCH) {
        int zi = idx - BATCH * DETER;
        int b = zi >> 9;
        float m = reset0[b] ? 0.f : 1.f;
        float4 v = *reinterpret_cast<const float4*>(z0 + zi);
        ushort4 o;
        o.x = f2bf(v.x * m); o.y = f2bf(v.y * m); o.z = f2bf(v.z * m); o.w = f2bf(v.w * m);
        *reinterpret_cast<ushort4*>(z16m + zi) = o;
    }
    if (blockIdx.x == 0 && threadIdx.x == 0) *ctr = 0u;
}

// ---------------- preA[r][j] = b_z[j] + sum_k action[r][k]*W_a[j][k]  (K=16)
__global__ __launch_bounds__(256) void k_preA(
    const float* __restrict__ action, const float* __restrict__ Wa,
    const float* __restrict__ bz, float* __restrict__ preA)
{
    __shared__ float al[16];
    int r = blockIdx.x, t = threadIdx.x;
    if (t < 16) al[t] = action[r * 16 + t];
    __syncthreads();
#pragma unroll
    for (int c = 0; c < 4; ++c) {
        int j = t + c * 256;
        const float* wr = Wa + j * 16;
        float s = bz[j];
#pragma unroll
        for (int k = 0; k < 16; ++k) s += al[k] * wr[k];
        preA[(size_t)r * 1024 + j] = s;
    }
}

// ---------------- one-shot MFMA GEMM (f32 sources, bf16 staging) -- from round 3
__global__ __launch_bounds__(256) void gemm_mfma(
    const float* __restrict__ A, int lda,
    const float* __restrict__ B, int ldb,
    const float* __restrict__ bias,
    float* __restrict__ C, int ldc, int K)
{
    __shared__ unsigned short Alds[64 * 72];
    __shared__ unsigned short Blds[64 * 72];
    int t = threadIdx.x;
    int nb = blockIdx.x, mb = blockIdx.y;
    int w = t >> 6, l = t & 63, l15 = l & 15, kg = l >> 4;
    f32x4 acc[4] = {{0,0,0,0},{0,0,0,0},{0,0,0,0},{0,0,0,0}};
    int srow = t >> 2, skq = (t & 3) * 16;
    const float* Asrc = A + (size_t)(mb * 64 + srow) * lda + skq;
    const float* Bsrc = B + (size_t)(nb * 64 + srow) * ldb + skq;
    unsigned short* Adst = &Alds[srow * 72 + skq];
    unsigned short* Bdst = &Blds[srow * 72 + skq];
    for (int kt = 0; kt < K; kt += 64) {
        __syncthreads();
#pragma unroll
        for (int c = 0; c < 16; c += 4) {
            float4 va = *reinterpret_cast<const float4*>(Asrc + kt + c);
            float4 vb = *reinterpret_cast<const float4*>(Bsrc + kt + c);
            ushort4 oa, ob;
            oa.x = f2bf(va.x); oa.y = f2bf(va.y); oa.z = f2bf(va.z); oa.w = f2bf(va.w);
            ob.x = f2bf(vb.x); ob.y = f2bf(vb.y); ob.z = f2bf(vb.z); ob.w = f2bf(vb.w);
            *reinterpret_cast<ushort4*>(Adst + c) = oa;
            *reinterpret_cast<ushort4*>(Bdst + c) = ob;
        }
        __syncthreads();
#pragma unroll
        for (int ks = 0; ks < 2; ks++) {
            bf16x8 a = *reinterpret_cast<const bf16x8*>(&Alds[(w * 16 + l15) * 72 + ks * 32 + kg * 8]);
#pragma unroll
            for (int nt = 0; nt < 4; nt++) {
                bf16x8 b = *reinterpret_cast<const bf16x8*>(&Blds[(nt * 16 + l15) * 72 + ks * 32 + kg * 8]);
                acc[nt] = MFMA16(a, b, acc[nt], 0, 0, 0);
            }
        }
    }
#pragma unroll
    for (int nt = 0; nt < 4; nt++) {
        int n = nb * 64 + nt * 16 + l15;
        float bv = bias[n];
#pragma unroll
        for (int i = 0; i < 4; i++) {
            C[(size_t)(mb * 64 + w * 16 + kg * 4 + i) * ldc + n] = acc[nt][i] + bv;
        }
    }
}

// ---------------- row LN+elu in place (f32), rows of 1024
__global__ __launch_bounds__(256) void ln_elu_rows(
    float* __restrict__ X, const float* __restrict__ g, const float* __restrict__ bb)
{
    __shared__ float sbuf[256], qbuf[256];
    int r = blockIdx.x, t = threadIdx.x;
    float* row = X + (size_t)r * HIDDEN;
    float4 v = reinterpret_cast<const float4*>(row)[t];
    sbuf[t] = (v.x + v.y) + (v.z + v.w);
    qbuf[t] = (v.x * v.x + v.y * v.y) + (v.z * v.z + v.w * v.w);
    __syncthreads();
    for (int off = 128; off > 0; off >>= 1) {
        if (t < off) { sbuf[t] += sbuf[t + off]; qbuf[t] += qbuf[t + off]; }
        __syncthreads();
    }
    float mean = sbuf[0] / HIDDEN;
    float var = qbuf[0] / HIDDEN - mean * mean;
    float rstd = rsqrtf(var + 1e-5f);
    float4 gg = reinterpret_cast<const float4*>(g)[t];
    float4 bv = reinterpret_cast<const float4*>(bb)[t];
    float4 o;
    o.x = eluf((v.x - mean) * rstd * gg.x + bv.x);
    o.y = eluf((v.y - mean) * rstd * gg.y + bv.y);
    o.z = eluf((v.z - mean) * rstd * gg.z + bv.z);
    o.w = eluf((v.w - mean) * rstd * gg.w + bv.w);
    reinterpret_cast<float4*>(row)[t] = o;
}

__global__ __launch_bounds__(256) void k_copy_last(
    const float* __restrict__ feat63, const float* __restrict__ samp63,
    float* __restrict__ hlast, float* __restrict__ zlast)
{
    int i = blockIdx.x * 256 + threadIdx.x;
    if (i < BATCH * DETER) {
        int b = i / DETER, k = i % DETER;
        hlast[i] = feat63[(size_t)b * FEAT + k];
    }
    if (i < BATCH * STOCH) zlast[i] = samp63[i];
}

// ======================= persistent cooperative scan =======================
struct ScanArgs {
    const unsigned short *Wz16, *Wih16, *Whh16, *Wph16, *Wpo16;
    const float *bih, *bhh, *b_post;
    const float *ln_in_g, *ln_in_b, *ln_post_g, *ln_post_b;
    const float *h0m;
    const uint8_t *reset;
    const float *noises;
    float *postsPreA;    // posts out region; preA prefilled per t-slice
    float *priorsPreE;   // priors out region; preE prefilled per t-slice
    float *samples;
    float *feats;
    unsigned short *z16m, *x1b, *x2b, *h16u, *h16m0, *h16m1;
    float *x1parts, *x2parts;   // [64][32][2]
    unsigned *ctr;
};

// per-row stats from 64 partial (sum,sumsq) records -> stat[0..31]=mean, [32..63]=rstd
__device__ __forceinline__ void ln_stats(const float* __restrict__ parts, float* stat, int tid) {
    if (tid < 32) {
        float s = 0.f, q = 0.f;
        for (int i = 0; i < 64; ++i) {
            s += parts[(i * 32 + tid) * 2];
            q += parts[(i * 32 + tid) * 2 + 1];
        }
        float mean = s * (1.f / 1024.f);
        float var = q * (1.f / 1024.f) - mean * mean;
        stat[tid] = mean;
        stat[32 + tid] = rsqrtf(var + 1e-5f);
    }
}

// LN+elu+cvt fill of padded LDS A-tile (32 rows x 1024, stride 1032 shorts)
__device__ __forceinline__ void ln_fill(unsigned short* Asm, const unsigned short* __restrict__ src,
                                        const float* __restrict__ g, const float* __restrict__ bb,
                                        const float* stat, int tid) {
    int row = tid & 31, kb = (tid >> 5) * 128;
    float mean = stat[row], rstd = stat[32 + row];
#pragma unroll 4
    for (int c = 0; c < 16; ++c) {
        int k = kb + c * 8;
        ushort4 u0 = *reinterpret_cast<const ushort4*>(src + row * 1024 + k);
        ushort4 u1 = *reinterpret_cast<const ushort4*>(src + row * 1024 + k + 4);
        float4 g0 = *reinterpret_cast<const float4*>(g + k);
        float4 g1 = *reinterpret_cast<const float4*>(g + k + 4);
        float4 b0 = *reinterpret_cast<const float4*>(bb + k);
        float4 b1 = *reinterpret_cast<const float4*>(bb + k + 4);
        ushort4 o0, o1;
        o0.x = f2bf(eluf((bf2f(u0.x) - mean) * rstd * g0.x + b0.x));
        o0.y = f2bf(eluf((bf2f(u0.y) - mean) * rstd * g0.y + b0.y));
        o0.z = f2bf(eluf((bf2f(u0.z) - mean) * rstd * g0.z + b0.z));
        o0.w = f2bf(eluf((bf2f(u0.w) - mean) * rstd * g0.w + b0.w));
        o1.x = f2bf(eluf((bf2f(u1.x) - mean) * rstd * g1.x + b1.x));
        o1.y = f2bf(eluf((bf2f(u1.y) - mean) * rstd * g1.y + b1.y));
        o1.z = f2bf(eluf((bf2f(u1.z) - mean) * rstd * g1.z + b1.z));
        o1.w = f2bf(eluf((bf2f(u1.w) - mean) * rstd * g1.w + b1.w));
        *reinterpret_cast<ushort4*>(Asm + row * 1032 + k) = o0;
        *reinterpret_cast<ushort4*>(Asm + row * 1032 + k + 4) = o1;
    }
}

__global__ __launch_bounds__(256, 1) void k_scan(ScanArgs a) {
    __shared__ char smem[74752];
    unsigned short* Asm = (unsigned short*)smem;       // 66048 B: 32 x 1032 bf16
    float* cbuf = (float*)(smem + 66048);              // 8 KB combine buffer
    float* stat = (float*)(smem + 66048 + 8192);       // 512 B

    const int bid = blockIdx.x;
    const int tid = threadIdx.x;
    const int w = tid >> 6, l = tid & 63, l15 = l & 15, kg = l >> 4;
    unsigned nbar = 0;

    for (int t = 0; t < NSTEP; ++t) {
        const float* preA_t = a.postsPreA + (size_t)t * 32768;
        const float* preE_t = a.priorsPreE + (size_t)t * 32768;
        float* posts_t = a.postsPreA + (size_t)t * 32768;
        float* samples_t = a.samples + (size_t)t * 16384;
        float* feats_t = a.feats + (size_t)t * 81920;
        const float* featsPrev = a.feats + (size_t)(t - 1) * 81920;
        const unsigned short* h16cur = (t & 1) ? a.h16m1 : a.h16m0;
        unsigned short* h16nxt = (t & 1) ? a.h16m0 : a.h16m1;

        // ---------- P1: x1 = preA + (m z) @ Wz^T  (64 blocks x 16 cols)
        if (bid < 64) {
            int j0 = bid * 16;
            const unsigned short* A0 = a.z16m + l15 * 512 + w * 128 + kg * 8;
            const unsigned short* A1 = A0 + 16 * 512;
            const unsigned short* Bp = a.Wz16 + (size_t)(j0 + l15) * 512 + w * 128 + kg * 8;
            f32x4 c0 = {0,0,0,0}, c1 = {0,0,0,0};
#pragma unroll
            for (int s = 0; s < 4; ++s) {
                bf16x8 b = *reinterpret_cast<const bf16x8*>(Bp + s * 32);
                c0 = MFMA16(*reinterpret_cast<const bf16x8*>(A0 + s * 32), b, c0, 0, 0, 0);
                c1 = MFMA16(*reinterpret_cast<const bf16x8*>(A1 + s * 32), b, c1, 0, 0, 0);
            }
#pragma unroll
            for (int i = 0; i < 4; ++i) {
                cbuf[w * 512 + (kg * 4 + i) * 16 + l15] = c0[i];
                cbuf[w * 512 + (16 + kg * 4 + i) * 16 + l15] = c1[i];
            }
            __syncthreads();
            int col = tid & 15, rr = tid >> 4;
#pragma unroll
            for (int half = 0; half < 2; ++half) {
                int r = rr + half * 16;
                float v = cbuf[r * 16 + col] + cbuf[512 + r * 16 + col]
                        + cbuf[1024 + r * 16 + col] + cbuf[1536 + r * 16 + col];
                v += preA_t[r * 1024 + j0 + col];
                unsigned short uv = f2bf(v);
                a.x1b[r * 1024 + j0 + col] = uv;
                float vf = bf2f(uv);
                float s = vf, q = vf * vf;
                s += __shfl_xor(s, 1); q += __shfl_xor(q, 1);
                s += __shfl_xor(s, 2); q += __shfl_xor(q, 2);
                s += __shfl_xor(s, 4); q += __shfl_xor(q, 4);
                s += __shfl_xor(s, 8); q += __shfl_xor(q, 8);
                if (col == 0) {
                    a.x1parts[(bid * 32 + r) * 2] = s;
                    a.x1parts[(bid * 32 + r) * 2 + 1] = q;
                }
            }
        }
        nbar++; gbar(a.ctr, nbar * NBLK);

        // ---------- P2: gates MFMA + GRU combine (128 blocks x 16 h-cols)
        if (bid < 128) {
            int j0 = bid * 16;
            ln_stats(a.x1parts, stat, tid);
            __syncthreads();
            ln_fill(Asm, a.x1b, a.ln_in_g, a.ln_in_b, stat, tid);
            __syncthreads();
            bool isI = (w < 2);
            int mt = w & 1;
            f32x4 cr = {0,0,0,0}, cu = {0,0,0,0}, cn = {0,0,0,0};
            if (isI) {
                const unsigned short* ap = Asm + (mt * 16 + l15) * 1032 + kg * 8;
                const unsigned short* br = a.Wih16 + (size_t)(j0 + l15) * 1024 + kg * 8;
                const unsigned short* bu = br + (size_t)2048 * 1024;
                const unsigned short* bn = bu + (size_t)2048 * 1024;
#pragma unroll 8
                for (int s = 0; s < 32; ++s) {
                    bf16x8 av = *reinterpret_cast<const bf16x8*>(ap + s * 32);
                    cr = MFMA16(av, *reinterpret_cast<const bf16x8*>(br + s * 32), cr, 0, 0, 0);
                    cu = MFMA16(av, *reinterpret_cast<const bf16x8*>(bu + s * 32), cu, 0, 0, 0);
                    cn = MFMA16(av, *reinterpret_cast<const bf16x8*>(bn + s * 32), cn, 0, 0, 0);
                }
            } else {
                const unsigned short* ap = h16cur + (size_t)(mt * 16 + l15) * 2048 + kg * 8;
                const unsigned short* br = a.Whh16 + (size_t)(j0 + l15) * 2048 + kg * 8;
                const unsigned short* bu = br + (size_t)2048 * 2048;
                const unsigned short* bn = bu + (size_t)2048 * 2048;
#pragma unroll 8
                for (int s = 0; s < 64; ++s) {
                    bf16x8 av = *reinterpret_cast<const bf16x8*>(ap + s * 32);
                    cr = MFMA16(av, *reinterpret_cast<const bf16x8*>(br + s * 32), cr, 0, 0, 0);
                    cu = MFMA16(av, *reinterpret_cast<const bf16x8*>(bu + s * 32), cu, 0, 0, 0);
                    cn = MFMA16(av, *reinterpret_cast<const bf16x8*>(bn + s * 32), cn, 0, 0, 0);
                }
#pragma unroll
                for (int i = 0; i < 4; ++i) {
                    cbuf[((mt * 3 + 0) * 16 + kg * 4 + i) * 16 + l15] = cr[i];
                    cbuf[((mt * 3 + 1) * 16 + kg * 4 + i) * 16 + l15] = cu[i];
                    cbuf[((mt * 3 + 2) * 16 + kg * 4 + i) * 16 + l15] = cn[i];
                }
            }
            __syncthreads();
            if (isI) {
                int j = j0 + l15;
                float bihr = a.bih[j], bihu = a.bih[j + 2048], bihn = a.bih[j + 4096];
                float bhhr = a.bhh[j], bhhu = a.bhh[j + 2048], bhhn = a.bhh[j + 4096];
#pragma unroll
                for (int i = 0; i < 4; ++i) {
                    int b = mt * 16 + kg * 4 + i;
                    float gr = cr[i] + bihr, gu = cu[i] + bihu, gn = cn[i] + bihn;
                    float hr = cbuf[((mt * 3 + 0) * 16 + kg * 4 + i) * 16 + l15] + bhhr;
                    float hu = cbuf[((mt * 3 + 1) * 16 + kg * 4 + i) * 16 + l15] + bhhu;
                    float hn = cbuf[((mt * 3 + 2) * 16 + kg * 4 + i) * 16 + l15] + bhhn;
                    float r = sigf(gr + hr), u = sigf(gu + hu);
                    float cand = tanhf(gn + r * hn);
                    float hpv = (t == 0) ? a.h0m[b * 2048 + j] : featsPrev[(size_t)b * 2560 + j];
                    float m = a.reset[t * 32 + b] ? 0.f : 1.f;
                    float hnew = (1.f - u) * cand + u * (m * hpv);
                    feats_t[(size_t)b * 2560 + j] = hnew;
                    a.h16u[b * 2048 + j] = f2bf(hnew);
                    float mn = (t < 63) ? (a.reset[(t + 1) * 32 + b] ? 0.f : 1.f) : 1.f;
                    h16nxt[b * 2048 + j] = f2bf(hnew * mn);
                }
            }
        }
        nbar++; gbar(a.ctr, nbar * NBLK);

        // ---------- P3: x2 = preE + h @ Wph^T  (64 blocks x 16 cols)
        if (bid < 64) {
            int j0 = bid * 16;
            const unsigned short* A0 = a.h16u + l15 * 2048 + w * 512 + kg * 8;
            const unsigned short* A1 = A0 + 16 * 2048;
            const unsigned short* Bp = a.Wph16 + (size_t)(j0 + l15) * 2048 + w * 512 + kg * 8;
            f32x4 c0 = {0,0,0,0}, c1 = {0,0,0,0};
#pragma unroll 8
            for (int s = 0; s < 16; ++s) {
                bf16x8 b = *reinterpret_cast<const bf16x8*>(Bp + s * 32);
                c0 = MFMA16(*reinterpret_cast<const bf16x8*>(A0 + s * 32), b, c0, 0, 0, 0);
                c1 = MFMA16(*reinterpret_cast<const bf16x8*>(A1 + s * 32), b, c1, 0, 0, 0);
            }
#pragma unroll
            for (int i = 0; i < 4; ++i) {
                cbuf[w * 512 + (kg * 4 + i) * 16 + l15] = c0[i];
                cbuf[w * 512 + (16 + kg * 4 + i) * 16 + l15] = c1[i];
            }
            __syncthreads();
            int col = tid & 15, rr = tid >> 4;
#pragma unroll
            for (int half = 0; half < 2; ++half) {
                int r = rr + half * 16;
                float v = cbuf[r * 16 + col] + cbuf[512 + r * 16 + col]
                        + cbuf[1024 + r * 16 + col] + cbuf[1536 + r * 16 + col];
                v += preE_t[r * 1024 + j0 + col];
                unsigned short uv = f2bf(v);
                a.x2b[r * 1024 + j0 + col] = uv;
                float vf = bf2f(uv);
                float s = vf, q = vf * vf;
                s += __shfl_xor(s, 1); q += __shfl_xor(q, 1);
                s += __shfl_xor(s, 2); q += __shfl_xor(q, 2);
                s += __shfl_xor(s, 4); q += __shfl_xor(q, 4);
                s += __shfl_xor(s, 8); q += __shfl_xor(q, 8);
                if (col == 0) {
                    a.x2parts[(bid * 32 + r) * 2] = s;
                    a.x2parts[(bid * 32 + r) * 2 + 1] = q;
                }
            }
        }
        nbar++; gbar(a.ctr, nbar * NBLK);

        // ---------- P4: post MFMA + sample  (32 blocks x 16 sample-cols)
        if (bid < 32) {
            int j0 = bid * 16;
            ln_stats(a.x2parts, stat, tid);
            __syncthreads();
            ln_fill(Asm, a.x2b, a.ln_post_g, a.ln_post_b, stat, tid);
            __syncthreads();
            int tile = w >> 1, mt = w & 1;
            const unsigned short* ap = Asm + (mt * 16 + l15) * 1032 + kg * 8;
            int n = (tile == 0) ? (j0 + l15) : (512 + j0 + l15);
            const unsigned short* Bp = a.Wpo16 + (size_t)n * 1024 + kg * 8;
            f32x4 c = {0,0,0,0};
#pragma unroll 8
            for (int s = 0; s < 32; ++s) {
                c = MFMA16(*reinterpret_cast<const bf16x8*>(ap + s * 32),
                           *reinterpret_cast<const bf16x8*>(Bp + s * 32), c, 0, 0, 0);
            }
#pragma unroll
            for (int i = 0; i < 4; ++i)
                cbuf[(tile * 2 + mt) * 256 + (kg * 4 + i) * 16 + l15] = c[i];
            __syncthreads();
            int col = tid & 15, rr = tid >> 4;
#pragma unroll
            for (int half = 0; half < 2; ++half) {
                int b = rr + half * 16;
                int j = j0 + col;
                float pm = cbuf[(0 * 2 + half) * 256 + rr * 16 + col] + a.b_post[j];
                float ps = cbuf[(1 * 2 + half) * 256 + rr * 16 + col] + a.b_post[512 + j];
                posts_t[(size_t)b * 1024 + j] = pm;
                posts_t[(size_t)b * 1024 + 512 + j] = ps;
                float sp = fmaxf(ps, 0.f) + log1pf(expf(-fabsf(ps)));
                float smp = pm + (sp + 0.1f) * a.noises[(size_t)t * 16384 + b * 512 + j];
                samples_t[(size_t)b * 512 + j] = smp;
                feats_t[(size_t)b * 2560 + 2048 + j] = smp;
                float mn = (t < 63) ? (a.reset[(t + 1) * 32 + b] ? 0.f : 1.f) : 1.f;
                a.z16m[b * 512 + j] = f2bf(smp * mn);
            }
        }
        nbar++; gbar(a.ctr, nbar * NBLK);
    }
}

// ws byte offsets
#define WS_WZ16   ((size_t)0)
#define WS_WIH16  ((size_t)1048576)
#define WS_WHH16  ((size_t)13631488)
#define WS_WPH16  ((size_t)38797312)
#define WS_WPO16  ((size_t)42991616)
#define WS_Z16M   ((size_t)45088768)
#define WS_H16M0  ((size_t)45121536)
#define WS_H16M1  ((size_t)45252608)
#define WS_H16U   ((size_t)45383680)
#define WS_H0M    ((size_t)45514752)
#define WS_X1B    ((size_t)45776896)
#define WS_X2B    ((size_t)45842432)
#define WS_X1P    ((size_t)45907968)
#define WS_X2P    ((size_t)45924352)
#define WS_CTR    ((size_t)45940736)
#define WS_PRX    WS_WIH16   // alias: Wih16 dead after scan (needs 8 MB <= 12.58 MB)

extern "C" void kernel_launch(void* const* d_in, const int* in_sizes, int n_in,
                              void* d_out, int out_size, void* d_ws, size_t ws_size,
                              hipStream_t stream)
{
    (void)in_sizes; (void)n_in; (void)out_size; (void)ws_size;
    const float*   embed  = (const float*)d_in[0];
    const float*   action = (const float*)d_in[1];
    const uint8_t* reset  = (const uint8_t*)d_in[2];
    const float*   h0     = (const float*)d_in[3];
    const float*   z0     = (const float*)d_in[4];
    const float*   noises = (const float*)d_in[5];
    const float*   W_z    = (const float*)d_in[6];
    const float*   b_z    = (const float*)d_in[7];
    const float*   W_a    = (const float*)d_in[8];
    const float*   ln_in_g = (const float*)d_in[9];
    const float*   ln_in_b = (const float*)d_in[10];
    const float*   Wih    = (const float*)d_in[11];
    const float*   Whh    = (const float*)d_in[12];
    const float*   bih    = (const float*)d_in[13];
    const float*   bhh    = (const float*)d_in[14];
    const float*   W_ph   = (const float*)d_in[15];
    const float*   b_ph   = (const float*)d_in[16];
    const float*   W_pe   = (const float*)d_in[17];
    const float*   ln_post_g = (const float*)d_in[18];
    const float*   ln_post_b = (const float*)d_in[19];
    const float*   W_post = (const float*)d_in[20];
    const float*   b_post = (const float*)d_in[21];
    const float*   W_prh  = (const float*)d_in[22];
    const float*   b_prh  = (const float*)d_in[23];
    const float*   ln_pr_g = (const float*)d_in[24];
    const float*   ln_pr_b = (const float*)d_in[25];
    const float*   W_pr   = (const float*)d_in[26];
    const float*   b_pr   = (const float*)d_in[27];

    float* out     = (float*)d_out;
    float* priors  = out;                  // preE lives here during scan
    float* posts   = out + 2097152;        // preA lives here during scan
    float* samples = out + 4194304;
    float* feats   = out + 5242880;
    float* hlast   = out + 10485760;
    float* zlast   = out + 10551296;

    char* ws = (char*)d_ws;
    unsigned short* Wz16  = (unsigned short*)(ws + WS_WZ16);
    unsigned short* Wih16 = (unsigned short*)(ws + WS_WIH16);
    unsigned short* Whh16 = (unsigned short*)(ws + WS_WHH16);
    unsigned short* Wph16 = (unsigned short*)(ws + WS_WPH16);
    unsigned short* Wpo16 = (unsigned short*)(ws + WS_WPO16);
    unsigned short* z16m  = (unsigned short*)(ws + WS_Z16M);
    unsigned short* h16m0 = (unsigned short*)(ws + WS_H16M0);
    unsigned short* h16m1 = (unsigned short*)(ws + WS_H16M1);
    unsigned short* h16u  = (unsigned short*)(ws + WS_H16U);
    float*          h0m   = (float*)(ws + WS_H0M);
    unsigned short* x1b   = (unsigned short*)(ws + WS_X1B);
    unsigned short* x2b   = (unsigned short*)(ws + WS_X2B);
    float*          x1p   = (float*)(ws + WS_X1P);
    float*          x2p   = (float*)(ws + WS_X2P);
    unsigned*       ctr   = (unsigned*)(ws + WS_CTR);
    float*          prx   = (float*)(ws + WS_PRX);

    dim3 blk(256);

    // setup: weight conversions, masked initial state, barrier counter reset
    k_cvt<<<dim3(512),   blk, 0, stream>>>(W_z,    Wz16,  524288);
    k_cvt<<<dim3(6144),  blk, 0, stream>>>(Wih,    Wih16, 6291456);
    k_cvt<<<dim3(12288), blk, 0, stream>>>(Whh,    Whh16, 12582912);
    k_cvt<<<dim3(2048),  blk, 0, stream>>>(W_ph,   Wph16, 2097152);
    k_cvt<<<dim3(1024),  blk, 0, stream>>>(W_post, Wpo16, 1048576);
    k_setup<<<dim3(80),  blk, 0, stream>>>(h0, z0, reset, h0m, h16m0, z16m, ctr);

    // preA -> posts region ; preE -> priors region
    k_preA<<<dim3(2048), blk, 0, stream>>>(action, W_a, b_z, posts);
    gemm_mfma<<<dim3(16, 32), blk, 0, stream>>>(embed, EMBED_D, W_pe, EMBED_D, b_ph,
                                                priors, HIDDEN, EMBED_D);

    // the whole 64-step scan: one cooperative kernel
    ScanArgs sa;
    sa.Wz16 = Wz16; sa.Wih16 = Wih16; sa.Whh16 = Whh16; sa.Wph16 = Wph16; sa.Wpo16 = Wpo16;
    sa.bih = bih; sa.bhh = bhh; sa.b_post = b_post;
    sa.ln_in_g = ln_in_g; sa.ln_in_b = ln_in_b; sa.ln_post_g = ln_post_g; sa.ln_post_b = ln_post_b;
    sa.h0m = h0m; sa.reset = reset; sa.noises = noises;
    sa.postsPreA = posts; sa.priorsPreE = priors; sa.samples = samples; sa.feats = feats;
    sa.z16m = z16m; sa.x1b = x1b; sa.x2b = x2b; sa.h16u = h16u;
    sa.h16m0 = h16m0; sa.h16m1 = h16m1;
    sa.x1parts = x1p; sa.x2parts = x2p; sa.ctr = ctr;
    void* kp[] = { (void*)&sa };
    hipLaunchCooperativeKernel((const void*)k_scan, dim3(NBLK), blk, kp, 0, stream);

    // prior chain
    gemm_mfma<<<dim3(16, 32), blk, 0, stream>>>(feats, FEAT, W_prh, DETER, b_prh,
                                                prx, HIDDEN, DETER);
    ln_elu_rows<<<dim3(2048), blk, 0, stream>>>(prx, ln_pr_g, ln_pr_b);
    gemm_mfma<<<dim3(16, 32), blk, 0, stream>>>(prx, HIDDEN, W_pr, HIDDEN, b_pr,
                                                priors, HIDDEN, HIDDEN);

    k_copy_last<<<dim3(256), blk, 0, stream>>>(
        feats + (size_t)(NSTEP - 1) * BATCH * FEAT,
        samples + (size_t)(NSTEP - 1) * BATCH * STOCH,
        hlast, zlast);
}

// Round 5
// 4743.623 us; speedup vs baseline: 1.7460x; 1.7460x over previous
//
#include <hip/hip_runtime.h>
#include <hip/hip_bf16.h>
#include <stdint.h>

#define NSTEP 64
#define BATCH 32
#define EMBED_D 1536
#define ACT_D 16
#define DETER 2048
#define STOCH 512
#define HIDDEN 1024
#define FEAT 2560
#define NBLK 256

typedef __attribute__((ext_vector_type(8))) short bf16x8;
typedef __attribute__((ext_vector_type(4))) float f32x4;

#define MFMA16 __builtin_amdgcn_mfma_f32_16x16x32_bf16
#define AGENT __HIP_MEMORY_SCOPE_AGENT

__device__ __forceinline__ float eluf(float x) { return x > 0.f ? x : expf(x) - 1.f; }
__device__ __forceinline__ float sigf(float x) { return 1.f / (1.f + expf(-x)); }
__device__ __forceinline__ unsigned short f2bf(float f) {
    __hip_bfloat16 h = __float2bfloat16(f);
    return __builtin_bit_cast(unsigned short, h);
}
__device__ __forceinline__ float bf2f(unsigned short u) {
    unsigned v = ((unsigned)u) << 16;
    return __builtin_bit_cast(float, v);
}

// ---- coherent (agent-scope, fence-free) access helpers: lower to sc1 ld/st
__device__ __forceinline__ void stc_u32(unsigned* p, unsigned v) {
    __hip_atomic_store(p, v, __ATOMIC_RELAXED, AGENT);
}
__device__ __forceinline__ void stc_u64(unsigned long long* p, unsigned long long v) {
    __hip_atomic_store(p, v, __ATOMIC_RELAXED, AGENT);
}
__device__ __forceinline__ unsigned long long ldc_u64(const unsigned long long* p) {
    return __hip_atomic_load(p, __ATOMIC_RELAXED, AGENT);
}
__device__ __forceinline__ float ldc_f32(const float* p) {
    return __hip_atomic_load(p, __ATOMIC_RELAXED, AGENT);
}
__device__ __forceinline__ int ldc_i32(const int* p) {
    return __hip_atomic_load(p, __ATOMIC_RELAXED, AGENT);
}
__device__ __forceinline__ void stc_i32(int* p, int v) {
    __hip_atomic_store(p, v, __ATOMIC_RELAXED, AGENT);
}
__device__ __forceinline__ bf16x8 ldc_bf8(const unsigned short* p) {
    union { unsigned long long q[2]; bf16x8 v; } u;
    u.q[0] = ldc_u64((const unsigned long long*)p);
    u.q[1] = ldc_u64((const unsigned long long*)(p + 4));
    return u.v;
}
__device__ __forceinline__ ushort4 ldc_us4(const unsigned short* p) {
    unsigned long long q = ldc_u64((const unsigned long long*)p);
    return __builtin_bit_cast(ushort4, q);
}

// ---- fence-free flag-tree grid barrier.
// arrival: per-block epoch flag (parallel sc1 stores, no RMW contention);
// block 0's threads poll one flag each; release via one flag. Ordering by
// vmcnt(0) drain (sc1 stores are at coherence point once retired) + syncthreads.
__device__ __forceinline__ void gbar2(int* flags, int* release, int epoch) {
    asm volatile("s_waitcnt vmcnt(0)" ::: "memory");
    __syncthreads();
    if (blockIdx.x == 0) {
        int tid = threadIdx.x;
        if (tid >= 1 && tid < NBLK) {
            while (ldc_i32(&flags[tid * 32]) < epoch) __builtin_amdgcn_s_sleep(4);
        }
        asm volatile("" ::: "memory");
        __syncthreads();
        if (tid == 0) stc_i32(release, epoch);
    } else {
        if (threadIdx.x == 0) {
            stc_i32(&flags[blockIdx.x * 32], epoch);
            while (ldc_i32(release) < epoch) __builtin_amdgcn_s_sleep(4);
        }
        asm volatile("" ::: "memory");
        __syncthreads();
    }
}

// ---------------- all weight conversions in one kernel (22544384 elements)
__global__ __launch_bounds__(256) void k_cvt_all(
    const float* __restrict__ s0, unsigned short* __restrict__ d0,
    const float* __restrict__ s1, unsigned short* __restrict__ d1,
    const float* __restrict__ s2, unsigned short* __restrict__ d2,
    const float* __restrict__ s3, unsigned short* __restrict__ d3,
    const float* __restrict__ s4, unsigned short* __restrict__ d4)
{
    long long e = ((long long)blockIdx.x * 256 + threadIdx.x) * 4;
    const float* src; unsigned short* dst; long long off;
    if (e < 524288)        { src = s0; dst = d0; off = e; }
    else if (e < 6815744)  { src = s1; dst = d1; off = e - 524288; }
    else if (e < 19398656) { src = s2; dst = d2; off = e - 6815744; }
    else if (e < 21495808) { src = s3; dst = d3; off = e - 19398656; }
    else if (e < 22544384) { src = s4; dst = d4; off = e - 21495808; }
    else return;
    float4 v = *reinterpret_cast<const float4*>(src + off);
    ushort4 o;
    o.x = f2bf(v.x); o.y = f2bf(v.y); o.z = f2bf(v.z); o.w = f2bf(v.w);
    *reinterpret_cast<ushort4*>(dst + off) = o;
}

// ---------------- setup: premasked h0 (f32+bf16), premasked z0 (bf16), flags=0
__global__ __launch_bounds__(256) void k_setup(
    const float* __restrict__ h0, const float* __restrict__ z0,
    const uint8_t* __restrict__ reset0,
    float* __restrict__ h0m, unsigned short* __restrict__ h16m0,
    unsigned short* __restrict__ z16m, int* __restrict__ flags)
{
    int gid = blockIdx.x * 256 + threadIdx.x;
    int idx = gid * 4;
    if (idx < BATCH * DETER) {
        int b = idx >> 11;
        float m = reset0[b] ? 0.f : 1.f;
        float4 v = *reinterpret_cast<const float4*>(h0 + idx);
        v.x *= m; v.y *= m; v.z *= m; v.w *= m;
        *reinterpret_cast<float4*>(h0m + idx) = v;
        ushort4 o;
        o.x = f2bf(v.x); o.y = f2bf(v.y); o.z = f2bf(v.z); o.w = f2bf(v.w);
        *reinterpret_cast<ushort4*>(h16m0 + idx) = o;
    } else if (idx < BATCH * DETER + BATCH * STOCH) {
        int zi = idx - BATCH * DETER;
        int b = zi >> 9;
        float m = reset0[b] ? 0.f : 1.f;
        float4 v = *reinterpret_cast<const float4*>(z0 + zi);
        ushort4 o;
        o.x = f2bf(v.x * m); o.y = f2bf(v.y * m); o.z = f2bf(v.z * m); o.w = f2bf(v.w * m);
        *reinterpret_cast<ushort4*>(z16m + zi) = o;
    }
    if (gid < 8224) flags[gid] = 0;   // 8192 flag ints + release pad
}

// ---------------- preA[r][j] = b_z[j] + sum_k action[r][k]*W_a[j][k]  (K=16)
__global__ __launch_bounds__(256) void k_preA(
    const float* __restrict__ action, const float* __restrict__ Wa,
    const float* __restrict__ bz, float* __restrict__ preA)
{
    __shared__ float al[16];
    int r = blockIdx.x, t = threadIdx.x;
    if (t < 16) al[t] = action[r * 16 + t];
    __syncthreads();
#pragma unroll
    for (int c = 0; c < 4; ++c) {
        int j = t + c * 256;
        const float* wr = Wa + j * 16;
        float s = bz[j];
#pragma unroll
        for (int k = 0; k < 16; ++k) s += al[k] * wr[k];
        preA[(size_t)r * 1024 + j] = s;
    }
}

// ---------------- one-shot MFMA GEMM (f32 sources, bf16 staging)
__global__ __launch_bounds__(256) void gemm_mfma(
    const float* __restrict__ A, int lda,
    const float* __restrict__ B, int ldb,
    const float* __restrict__ bias,
    float* __restrict__ C, int ldc, int K)
{
    __shared__ unsigned short Alds[64 * 72];
    __shared__ unsigned short Blds[64 * 72];
    int t = threadIdx.x;
    int nb = blockIdx.x, mb = blockIdx.y;
    int w = t >> 6, l = t & 63, l15 = l & 15, kg = l >> 4;
    f32x4 acc[4] = {{0,0,0,0},{0,0,0,0},{0,0,0,0},{0,0,0,0}};
    int srow = t >> 2, skq = (t & 3) * 16;
    const float* Asrc = A + (size_t)(mb * 64 + srow) * lda + skq;
    const float* Bsrc = B + (size_t)(nb * 64 + srow) * ldb + skq;
    unsigned short* Adst = &Alds[srow * 72 + skq];
    unsigned short* Bdst = &Blds[srow * 72 + skq];
    for (int kt = 0; kt < K; kt += 64) {
        __syncthreads();
#pragma unroll
        for (int c = 0; c < 16; c += 4) {
            float4 va = *reinterpret_cast<const float4*>(Asrc + kt + c);
            float4 vb = *reinterpret_cast<const float4*>(Bsrc + kt + c);
            ushort4 oa, ob;
            oa.x = f2bf(va.x); oa.y = f2bf(va.y); oa.z = f2bf(va.z); oa.w = f2bf(va.w);
            ob.x = f2bf(vb.x); ob.y = f2bf(vb.y); ob.z = f2bf(vb.z); ob.w = f2bf(vb.w);
            *reinterpret_cast<ushort4*>(Adst + c) = oa;
            *reinterpret_cast<ushort4*>(Bdst + c) = ob;
        }
        __syncthreads();
#pragma unroll
        for (int ks = 0; ks < 2; ks++) {
            bf16x8 a = *reinterpret_cast<const bf16x8*>(&Alds[(w * 16 + l15) * 72 + ks * 32 + kg * 8]);
#pragma unroll
            for (int nt = 0; nt < 4; nt++) {
                bf16x8 b = *reinterpret_cast<const bf16x8*>(&Blds[(nt * 16 + l15) * 72 + ks * 32 + kg * 8]);
                acc[nt] = MFMA16(a, b, acc[nt], 0, 0, 0);
            }
        }
    }
#pragma unroll
    for (int nt = 0; nt < 4; nt++) {
        int n = nb * 64 + nt * 16 + l15;
        float bv = bias[n];
#pragma unroll
        for (int i = 0; i < 4; i++) {
            C[(size_t)(mb * 64 + w * 16 + kg * 4 + i) * ldc + n] = acc[nt][i] + bv;
        }
    }
}

// ---------------- row LN+elu in place (f32), rows of 1024
__global__ __launch_bounds__(256) void ln_elu_rows(
    float* __restrict__ X, const float* __restrict__ g, const float* __restrict__ bb)
{
    __shared__ float sbuf[256], qbuf[256];
    int r = blockIdx.x, t = threadIdx.x;
    float* row = X + (size_t)r * HIDDEN;
    float4 v = reinterpret_cast<const float4*>(row)[t];
    sbuf[t] = (v.x + v.y) + (v.z + v.w);
    qbuf[t] = (v.x * v.x + v.y * v.y) + (v.z * v.z + v.w * v.w);
    __syncthreads();
    for (int off = 128; off > 0; off >>= 1) {
        if (t < off) { sbuf[t] += sbuf[t + off]; qbuf[t] += qbuf[t + off]; }
        __syncthreads();
    }
    float mean = sbuf[0] / HIDDEN;
    float var = qbuf[0] / HIDDEN - mean * mean;
    float rstd = rsqrtf(var + 1e-5f);
    float4 gg = reinterpret_cast<const float4*>(g)[t];
    float4 bv = reinterpret_cast<const float4*>(bb)[t];
    float4 o;
    o.x = eluf((v.x - mean) * rstd * gg.x + bv.x);
    o.y = eluf((v.y - mean) * rstd * gg.y + bv.y);
    o.z = eluf((v.z - mean) * rstd * gg.z + bv.z);
    o.w = eluf((v.w - mean) * rstd * gg.w + bv.w);
    reinterpret_cast<float4*>(row)[t] = o;
}

__global__ __launch_bounds__(256) void k_copy_last(
    const float* __restrict__ feat63, const float* __restrict__ samp63,
    float* __restrict__ hlast, float* __restrict__ zlast)
{
    int i = blockIdx.x * 256 + threadIdx.x;
    if (i < BATCH * DETER) {
        int b = i / DETER, k = i % DETER;
        hlast[i] = feat63[(size_t)b * FEAT + k];
    }
    if (i < BATCH * STOCH) zlast[i] = samp63[i];
}

// ======================= persistent cooperative scan =======================
struct ScanArgs {
    const unsigned short *Wz16, *Wih16, *Whh16, *Wph16, *Wpo16;
    const float *bih, *bhh, *b_post;
    const float *ln_in_g, *ln_in_b, *ln_post_g, *ln_post_b;
    const float *h0m;
    const uint8_t *reset;
    const float *noises;
    float *postsPreA;
    float *priorsPreE;
    float *samples;
    float *feats;
    unsigned short *z16m, *x1b, *x2b, *h16u, *h16m0, *h16m1;
    float *x1parts, *x2parts;   // [64][32][2]
    int *flags, *release;
};

__device__ __forceinline__ void ln_stats(const float* __restrict__ parts, float* stat, int tid) {
    if (tid < 32) {
        float s = 0.f, q = 0.f;
        for (int i = 0; i < 64; ++i) {
            union { unsigned long long u; float f[2]; } c;
            c.u = ldc_u64((const unsigned long long*)(parts + (size_t)(i * 32 + tid) * 2));
            s += c.f[0]; q += c.f[1];
        }
        float mean = s * (1.f / 1024.f);
        float var = q * (1.f / 1024.f) - mean * mean;
        stat[tid] = mean;
        stat[32 + tid] = rsqrtf(var + 1e-5f);
    }
}

__device__ __forceinline__ void ln_fill(unsigned short* Asm, const unsigned short* __restrict__ src,
                                        const float* __restrict__ g, const float* __restrict__ bb,
                                        const float* stat, int tid) {
    int row = tid & 31, kb = (tid >> 5) * 128;
    float mean = stat[row], rstd = stat[32 + row];
#pragma unroll 4
    for (int c = 0; c < 16; ++c) {
        int k = kb + c * 8;
        ushort4 u0 = ldc_us4(src + (size_t)row * 1024 + k);
        ushort4 u1 = ldc_us4(src + (size_t)row * 1024 + k + 4);
        float4 g0 = *reinterpret_cast<const float4*>(g + k);
        float4 g1 = *reinterpret_cast<const float4*>(g + k + 4);
        float4 b0 = *reinterpret_cast<const float4*>(bb + k);
        float4 b1 = *reinterpret_cast<const float4*>(bb + k + 4);
        ushort4 o0, o1;
        o0.x = f2bf(eluf((bf2f(u0.x) - mean) * rstd * g0.x + b0.x));
        o0.y = f2bf(eluf((bf2f(u0.y) - mean) * rstd * g0.y + b0.y));
        o0.z = f2bf(eluf((bf2f(u0.z) - mean) * rstd * g0.z + b0.z));
        o0.w = f2bf(eluf((bf2f(u0.w) - mean) * rstd * g0.w + b0.w));
        o1.x = f2bf(eluf((bf2f(u1.x) - mean) * rstd * g1.x + b1.x));
        o1.y = f2bf(eluf((bf2f(u1.y) - mean) * rstd * g1.y + b1.y));
        o1.z = f2bf(eluf((bf2f(u1.z) - mean) * rstd * g1.z + b1.z));
        o1.w = f2bf(eluf((bf2f(u1.w) - mean) * rstd * g1.w + b1.w));
        *reinterpret_cast<ushort4*>(Asm + row * 1032 + k) = o0;
        *reinterpret_cast<ushort4*>(Asm + row * 1032 + k + 4) = o1;
    }
}

__global__ __launch_bounds__(256, 1) void k_scan(ScanArgs a) {
    __shared__ char smem[74752];
    unsigned short* Asm = (unsigned short*)smem;       // 66048 B: 32 x 1032 bf16
    float* cbuf = (float*)(smem + 66048);              // 8 KB (2048 floats)
    float* stat = (float*)(smem + 66048 + 8192);       // 512 B

    const int bid = blockIdx.x;
    const int tid = threadIdx.x;
    const int w = tid >> 6, l = tid & 63, l15 = l & 15, kg = l >> 4;
    int epoch = 0;

    for (int t = 0; t < NSTEP; ++t) {
        const float* preA_t = a.postsPreA + (size_t)t * 32768;
        const float* preE_t = a.priorsPreE + (size_t)t * 32768;
        float* posts_t = a.postsPreA + (size_t)t * 32768;
        float* samples_t = a.samples + (size_t)t * 16384;
        float* feats_t = a.feats + (size_t)t * 81920;
        const float* featsPrev = a.feats + (size_t)(t - 1) * 81920;
        const unsigned short* h16cur = (t & 1) ? a.h16m1 : a.h16m0;
        unsigned short* h16nxt = (t & 1) ? a.h16m0 : a.h16m1;

        // ---------- P1: x1 = preA + (m z) @ Wz^T  (64 blocks x 16 cols)
        if (bid < 64) {
            int j0 = bid * 16;
            const unsigned short* A0 = a.z16m + l15 * 512 + w * 128 + kg * 8;
            const unsigned short* A1 = A0 + 16 * 512;
            const unsigned short* Bp = a.Wz16 + (size_t)(j0 + l15) * 512 + w * 128 + kg * 8;
            f32x4 c0 = {0,0,0,0}, c1 = {0,0,0,0};
#pragma unroll
            for (int ks = 0; ks < 4; ++ks) {
                bf16x8 b = *reinterpret_cast<const bf16x8*>(Bp + ks * 32);
                c0 = MFMA16(ldc_bf8(A0 + ks * 32), b, c0, 0, 0, 0);
                c1 = MFMA16(ldc_bf8(A1 + ks * 32), b, c1, 0, 0, 0);
            }
#pragma unroll
            for (int i = 0; i < 4; ++i) {
                cbuf[w * 512 + (kg * 4 + i) * 16 + l15] = c0[i];
                cbuf[w * 512 + (16 + kg * 4 + i) * 16 + l15] = c1[i];
            }
            __syncthreads();
            int r = tid >> 3, c2 = (tid & 7) * 2;
            int base = r * 16 + c2;
            float v0 = cbuf[base] + cbuf[512 + base] + cbuf[1024 + base] + cbuf[1536 + base]
                     + preA_t[r * 1024 + j0 + c2];
            float v1 = cbuf[base + 1] + cbuf[512 + base + 1] + cbuf[1024 + base + 1] + cbuf[1536 + base + 1]
                     + preA_t[r * 1024 + j0 + c2 + 1];
            unsigned short u0 = f2bf(v0), u1 = f2bf(v1);
            stc_u32((unsigned*)(a.x1b + (size_t)r * 1024 + j0 + c2),
                    (unsigned)u0 | ((unsigned)u1 << 16));
            float w0 = bf2f(u0), w1 = bf2f(u1);
            float s = w0 + w1, q = w0 * w0 + w1 * w1;
            s += __shfl_xor(s, 1); q += __shfl_xor(q, 1);
            s += __shfl_xor(s, 2); q += __shfl_xor(q, 2);
            s += __shfl_xor(s, 4); q += __shfl_xor(q, 4);
            if ((tid & 7) == 0) {
                union { float f[2]; unsigned long long u; } pu;
                pu.f[0] = s; pu.f[1] = q;
                stc_u64((unsigned long long*)(a.x1parts + ((size_t)bid * 32 + r) * 2), pu.u);
            }
        }
        epoch++; gbar2(a.flags, a.release, epoch);

        // ---------- P2: gates MFMA + GRU combine (128 blocks x 16 h-cols)
        if (bid < 128) {
            int j0 = bid * 16;
            ln_stats(a.x1parts, stat, tid);
            __syncthreads();
            ln_fill(Asm, a.x1b, a.ln_in_g, a.ln_in_b, stat, tid);
            __syncthreads();
            bool isI = (w < 2);
            int mt = w & 1;
            f32x4 cr = {0,0,0,0}, cu = {0,0,0,0}, cn = {0,0,0,0};
            if (isI) {
                const unsigned short* ap = Asm + (mt * 16 + l15) * 1032 + kg * 8;
                const unsigned short* br = a.Wih16 + (size_t)(j0 + l15) * 1024 + kg * 8;
                const unsigned short* bu = br + (size_t)2048 * 1024;
                const unsigned short* bn = bu + (size_t)2048 * 1024;
#pragma unroll 8
                for (int ks = 0; ks < 32; ++ks) {
                    bf16x8 av = *reinterpret_cast<const bf16x8*>(ap + ks * 32);
                    cr = MFMA16(av, *reinterpret_cast<const bf16x8*>(br + ks * 32), cr, 0, 0, 0);
                    cu = MFMA16(av, *reinterpret_cast<const bf16x8*>(bu + ks * 32), cu, 0, 0, 0);
                    cn = MFMA16(av, *reinterpret_cast<const bf16x8*>(bn + ks * 32), cn, 0, 0, 0);
                }
            } else {
                const unsigned short* ap = h16cur + (size_t)(mt * 16 + l15) * 2048 + kg * 8;
                const unsigned short* br = a.Whh16 + (size_t)(j0 + l15) * 2048 + kg * 8;
                const unsigned short* bu = br + (size_t)2048 * 2048;
                const unsigned short* bn = bu + (size_t)2048 * 2048;
#pragma unroll 8
                for (int ks = 0; ks < 64; ++ks) {
                    bf16x8 av = ldc_bf8(ap + ks * 32);
                    cr = MFMA16(av, *reinterpret_cast<const bf16x8*>(br + ks * 32), cr, 0, 0, 0);
                    cu = MFMA16(av, *reinterpret_cast<const bf16x8*>(bu + ks * 32), cu, 0, 0, 0);
                    cn = MFMA16(av, *reinterpret_cast<const bf16x8*>(bn + ks * 32), cn, 0, 0, 0);
                }
#pragma unroll
                for (int i = 0; i < 4; ++i) {
                    cbuf[((mt * 3 + 0) * 16 + kg * 4 + i) * 16 + l15] = cr[i];
                    cbuf[((mt * 3 + 1) * 16 + kg * 4 + i) * 16 + l15] = cu[i];
                    cbuf[((mt * 3 + 2) * 16 + kg * 4 + i) * 16 + l15] = cn[i];
                }
            }
            __syncthreads();
            if (isI) {
                int j = j0 + l15;
                float bihr = a.bih[j], bihu = a.bih[j + 2048], bihn = a.bih[j + 4096];
                float bhhr = a.bhh[j], bhhu = a.bhh[j + 2048], bhhn = a.bhh[j + 4096];
#pragma unroll
                for (int i = 0; i < 4; ++i) {
                    int b = mt * 16 + kg * 4 + i;
                    float gr = cr[i] + bihr, gu = cu[i] + bihu, gn = cn[i] + bihn;
                    float hr = cbuf[((mt * 3 + 0) * 16 + kg * 4 + i) * 16 + l15] + bhhr;
                    float hu = cbuf[((mt * 3 + 1) * 16 + kg * 4 + i) * 16 + l15] + bhhu;
                    float hn = cbuf[((mt * 3 + 2) * 16 + kg * 4 + i) * 16 + l15] + bhhn;
                    float r = sigf(gr + hr), u = sigf(gu + hu);
                    float cand = tanhf(gn + r * hn);
                    float m = a.reset[t * 32 + b] ? 0.f : 1.f;
                    float hpv = (t == 0) ? a.h0m[b * 2048 + j]
                                         : ldc_f32(featsPrev + (size_t)b * 2560 + j);
                    float hnew = (1.f - u) * cand + u * (m * hpv);
                    cbuf[1536 + b * 16 + l15] = hnew;
                }
            }
            __syncthreads();
            {
                int b = tid >> 3, c2 = (tid & 7) * 2;
                float h0v = cbuf[1536 + b * 16 + c2], h1v = cbuf[1536 + b * 16 + c2 + 1];
                int j = j0 + c2;
                union { float f[2]; unsigned long long u; } fu;
                fu.f[0] = h0v; fu.f[1] = h1v;
                stc_u64((unsigned long long*)(feats_t + (size_t)b * 2560 + j), fu.u);
                unsigned short g0 = f2bf(h0v), g1 = f2bf(h1v);
                stc_u32((unsigned*)(a.h16u + (size_t)b * 2048 + j),
                        (unsigned)g0 | ((unsigned)g1 << 16));
                float mn = (t < 63) ? (a.reset[(t + 1) * 32 + b] ? 0.f : 1.f) : 1.f;
                unsigned short n0 = f2bf(h0v * mn), n1 = f2bf(h1v * mn);
                stc_u32((unsigned*)(h16nxt + (size_t)b * 2048 + j),
                        (unsigned)n0 | ((unsigned)n1 << 16));
            }
        }
        epoch++; gbar2(a.flags, a.release, epoch);

        // ---------- P3: x2 = preE + h @ Wph^T  (64 blocks x 16 cols)
        if (bid < 64) {
            int j0 = bid * 16;
            const unsigned short* A0 = a.h16u + l15 * 2048 + w * 512 + kg * 8;
            const unsigned short* A1 = A0 + 16 * 2048;
            const unsigned short* Bp = a.Wph16 + (size_t)(j0 + l15) * 2048 + w * 512 + kg * 8;
            f32x4 c0 = {0,0,0,0}, c1 = {0,0,0,0};
#pragma unroll 8
            for (int ks = 0; ks < 16; ++ks) {
                bf16x8 b = *reinterpret_cast<const bf16x8*>(Bp + ks * 32);
                c0 = MFMA16(ldc_bf8(A0 + ks * 32), b, c0, 0, 0, 0);
                c1 = MFMA16(ldc_bf8(A1 + ks * 32), b, c1, 0, 0, 0);
            }
#pragma unroll
            for (int i = 0; i < 4; ++i) {
                cbuf[w * 512 + (kg * 4 + i) * 16 + l15] = c0[i];
                cbuf[w * 512 + (16 + kg * 4 + i) * 16 + l15] = c1[i];
            }
            __syncthreads();
            int r = tid >> 3, c2 = (tid & 7) * 2;
            int base = r * 16 + c2;
            float v0 = cbuf[base] + cbuf[512 + base] + cbuf[1024 + base] + cbuf[1536 + base]
                     + preE_t[r * 1024 + j0 + c2];
            float v1 = cbuf[base + 1] + cbuf[512 + base + 1] + cbuf[1024 + base + 1] + cbuf[1536 + base + 1]
                     + preE_t[r * 1024 + j0 + c2 + 1];
            unsigned short u0 = f2bf(v0), u1 = f2bf(v1);
            stc_u32((unsigned*)(a.x2b + (size_t)r * 1024 + j0 + c2),
                    (unsigned)u0 | ((unsigned)u1 << 16));
            float w0 = bf2f(u0), w1 = bf2f(u1);
            float s = w0 + w1, q = w0 * w0 + w1 * w1;
            s += __shfl_xor(s, 1); q += __shfl_xor(q, 1);
            s += __shfl_xor(s, 2); q += __shfl_xor(q, 2);
            s += __shfl_xor(s, 4); q += __shfl_xor(q, 4);
            if ((tid & 7) == 0) {
                union { float f[2]; unsigned long long u; } pu;
                pu.f[0] = s; pu.f[1] = q;
                stc_u64((unsigned long long*)(a.x2parts + ((size_t)bid * 32 + r) * 2), pu.u);
            }
        }
        epoch++; gbar2(a.flags, a.release, epoch);

        // ---------- P4: post MFMA + sample  (32 blocks x 16 sample-cols)
        if (bid < 32) {
            int j0 = bid * 16;
            ln_stats(a.x2parts, stat, tid);
            __syncthreads();
            ln_fill(Asm, a.x2b, a.ln_post_g, a.ln_post_b, stat, tid);
            __syncthreads();
            int tile = w >> 1, mt = w & 1;
            const unsigned short* ap = Asm + (mt * 16 + l15) * 1032 + kg * 8;
            int n = (tile == 0) ? (j0 + l15) : (512 + j0 + l15);
            const unsigned short* Bp = a.Wpo16 + (size_t)n * 1024 + kg * 8;
            f32x4 c = {0,0,0,0};
#pragma unroll 8
            for (int ks = 0; ks < 32; ++ks) {
                c = MFMA16(*reinterpret_cast<const bf16x8*>(ap + ks * 32),
                           *reinterpret_cast<const bf16x8*>(Bp + ks * 32), c, 0, 0, 0);
            }
#pragma unroll
            for (int i = 0; i < 4; ++i)
                cbuf[(tile * 2 + mt) * 256 + (kg * 4 + i) * 16 + l15] = c[i];
            __syncthreads();
            int b = tid >> 3, c2 = (tid & 7) * 2;
            int j = j0 + c2;
            int ib = (b >> 4) * 256 + (b & 15) * 16;
            float pm0 = cbuf[ib + c2] + a.b_post[j];
            float pm1 = cbuf[ib + c2 + 1] + a.b_post[j + 1];
            float ps0 = cbuf[512 + ib + c2] + a.b_post[512 + j];
            float ps1 = cbuf[512 + ib + c2 + 1] + a.b_post[512 + j + 1];
            posts_t[(size_t)b * 1024 + j] = pm0;
            posts_t[(size_t)b * 1024 + j + 1] = pm1;
            posts_t[(size_t)b * 1024 + 512 + j] = ps0;
            posts_t[(size_t)b * 1024 + 512 + j + 1] = ps1;
            float sp0 = fmaxf(ps0, 0.f) + log1pf(expf(-fabsf(ps0)));
            float sp1 = fmaxf(ps1, 0.f) + log1pf(expf(-fabsf(ps1)));
            float n0v = a.noises[(size_t)t * 16384 + b * 512 + j];
            float n1v = a.noises[(size_t)t * 16384 + b * 512 + j + 1];
            float smp0 = pm0 + (sp0 + 0.1f) * n0v;
            float smp1 = pm1 + (sp1 + 0.1f) * n1v;
            samples_t[(size_t)b * 512 + j] = smp0;
            samples_t[(size_t)b * 512 + j + 1] = smp1;
            feats_t[(size_t)b * 2560 + 2048 + j] = smp0;
            feats_t[(size_t)b * 2560 + 2048 + j + 1] = smp1;
            float mn = (t < 63) ? (a.reset[(t + 1) * 32 + b] ? 0.f : 1.f) : 1.f;
            unsigned short z0_ = f2bf(smp0 * mn), z1_ = f2bf(smp1 * mn);
            stc_u32((unsigned*)(a.z16m + (size_t)b * 512 + j),
                    (unsigned)z0_ | ((unsigned)z1_ << 16));
        }
        epoch++; gbar2(a.flags, a.release, epoch);
    }
}

// ws byte offsets
#define WS_WZ16   ((size_t)0)
#define WS_WIH16  ((size_t)1048576)
#define WS_WHH16  ((size_t)13631488)
#define WS_WPH16  ((size_t)38797312)
#define WS_WPO16  ((size_t)42991616)
#define WS_Z16M   ((size_t)45088768)
#define WS_H16M0  ((size_t)45121536)
#define WS_H16M1  ((size_t)45252608)
#define WS_H16U   ((size_t)45383680)
#define WS_H0M    ((size_t)45514752)
#define WS_X1B    ((size_t)45776896)
#define WS_X2B    ((size_t)45842432)
#define WS_X1P    ((size_t)45907968)
#define WS_X2P    ((size_t)45924352)
#define WS_FLAGS  ((size_t)45940736)
#define WS_REL    ((size_t)45973504)
#define WS_PRX    WS_WIH16   // alias: Wih16 dead after scan

extern "C" void kernel_launch(void* const* d_in, const int* in_sizes, int n_in,
                              void* d_out, int out_size, void* d_ws, size_t ws_size,
                              hipStream_t stream)
{
    (void)in_sizes; (void)n_in; (void)out_size; (void)ws_size;
    const float*   embed  = (const float*)d_in[0];
    const float*   action = (const float*)d_in[1];
    const uint8_t* reset  = (const uint8_t*)d_in[2];
    const float*   h0     = (const float*)d_in[3];
    const float*   z0     = (const float*)d_in[4];
    const float*   noises = (const float*)d_in[5];
    const float*   W_z    = (const float*)d_in[6];
    const float*   b_z    = (const float*)d_in[7];
    const float*   W_a    = (const float*)d_in[8];
    const float*   ln_in_g = (const float*)d_in[9];
    const float*   ln_in_b = (const float*)d_in[10];
    const float*   Wih    = (const float*)d_in[11];
    const float*   Whh    = (const float*)d_in[12];
    const float*   bih    = (const float*)d_in[13];
    const float*   bhh    = (const float*)d_in[14];
    const float*   W_ph   = (const float*)d_in[15];
    const float*   b_ph   = (const float*)d_in[16];
    const float*   W_pe   = (const float*)d_in[17];
    const float*   ln_post_g = (const float*)d_in[18];
    const float*   ln_post_b = (const float*)d_in[19];
    const float*   W_post = (const float*)d_in[20];
    const float*   b_post = (const float*)d_in[21];
    const float*   W_prh  = (const float*)d_in[22];
    const float*   b_prh  = (const float*)d_in[23];
    const float*   ln_pr_g = (const float*)d_in[24];
    const float*   ln_pr_b = (const float*)d_in[25];
    const float*   W_pr   = (const float*)d_in[26];
    const float*   b_pr   = (const float*)d_in[27];

    float* out     = (float*)d_out;
    float* priors  = out;                  // preE lives here during scan
    float* posts   = out + 2097152;        // preA lives here during scan
    float* samples = out + 4194304;
    float* feats   = out + 5242880;
    float* hlast   = out + 10485760;
    float* zlast   = out + 10551296;

    char* ws = (char*)d_ws;
    unsigned short* Wz16  = (unsigned short*)(ws + WS_WZ16);
    unsigned short* Wih16 = (unsigned short*)(ws + WS_WIH16);
    unsigned short* Whh16 = (unsigned short*)(ws + WS_WHH16);
    unsigned short* Wph16 = (unsigned short*)(ws + WS_WPH16);
    unsigned short* Wpo16 = (unsigned short*)(ws + WS_WPO16);
    unsigned short* z16m  = (unsigned short*)(ws + WS_Z16M);
    unsigned short* h16m0 = (unsigned short*)(ws + WS_H16M0);
    unsigned short* h16m1 = (unsigned short*)(ws + WS_H16M1);
    unsigned short* h16u  = (unsigned short*)(ws + WS_H16U);
    float*          h0m   = (float*)(ws + WS_H0M);
    unsigned short* x1b   = (unsigned short*)(ws + WS_X1B);
    unsigned short* x2b   = (unsigned short*)(ws + WS_X2B);
    float*          x1p   = (float*)(ws + WS_X1P);
    float*          x2p   = (float*)(ws + WS_X2P);
    int*            flags = (int*)(ws + WS_FLAGS);
    int*            release = (int*)(ws + WS_REL);
    float*          prx   = (float*)(ws + WS_PRX);

    dim3 blk(256);

    // setup
    k_cvt_all<<<dim3(22016), blk, 0, stream>>>(W_z, Wz16, Wih, Wih16, Whh, Whh16,
                                               W_ph, Wph16, W_post, Wpo16);
    k_setup<<<dim3(80), blk, 0, stream>>>(h0, z0, reset, h0m, h16m0, z16m, flags);

    // preA -> posts region ; preE -> priors region
    k_preA<<<dim3(2048), blk, 0, stream>>>(action, W_a, b_z, posts);
    gemm_mfma<<<dim3(16, 32), blk, 0, stream>>>(embed, EMBED_D, W_pe, EMBED_D, b_ph,
                                                priors, HIDDEN, EMBED_D);

    // the whole 64-step scan: one cooperative kernel, fence-free barriers
    ScanArgs sa;
    sa.Wz16 = Wz16; sa.Wih16 = Wih16; sa.Whh16 = Whh16; sa.Wph16 = Wph16; sa.Wpo16 = Wpo16;
    sa.bih = bih; sa.bhh = bhh; sa.b_post = b_post;
    sa.ln_in_g = ln_in_g; sa.ln_in_b = ln_in_b; sa.ln_post_g = ln_post_g; sa.ln_post_b = ln_post_b;
    sa.h0m = h0m; sa.reset = reset; sa.noises = noises;
    sa.postsPreA = posts; sa.priorsPreE = priors; sa.samples = samples; sa.feats = feats;
    sa.z16m = z16m; sa.x1b = x1b; sa.x2b = x2b; sa.h16u = h16u;
    sa.h16m0 = h16m0; sa.h16m1 = h16m1;
    sa.x1parts = x1p; sa.x2parts = x2p;
    sa.flags = flags; sa.release = release;
    void* kp[] = { (void*)&sa };
    hipLaunchCooperativeKernel((const void*)k_scan, dim3(NBLK), blk, kp, 0, stream);

    // prior chain
    gemm_mfma<<<dim3(16, 32), blk, 0, stream>>>(feats, FEAT, W_prh, DETER, b_prh,
                                                prx, HIDDEN, DETER);
    ln_elu_rows<<<dim3(2048), blk, 0, stream>>>(prx, ln_pr_g, ln_pr_b);
    gemm_mfma<<<dim3(16, 32), blk, 0, stream>>>(prx, HIDDEN, W_pr, HIDDEN, b_pr,
                                                priors, HIDDEN, HIDDEN);

    k_copy_last<<<dim3(256), blk, 0, stream>>>(
        feats + (size_t)(NSTEP - 1) * BATCH * FEAT,
        samples + (size_t)(NSTEP - 1) * BATCH * STOCH,
        hlast, zlast);
}